// Round 9
// baseline (614.907 us; speedup 1.0000x reference)
//
#include <hip/hip_runtime.h>

#define N_NODES 50000
#define N_EDGES 800000
#define C 128
#define BN_EPS 1e-5f
#define BSHIFT 7                              // 128 nodes per bucket
#define NBUCK ((N_NODES + 127) >> BSHIFT)     // 391
#define EPB 2048                              // edges per scat unit
#define A_BLOCKS ((N_EDGES + EPB - 1) / EPB)  // 391
#define EBUF 2560                             // per-bucket staging cap (mean 2046, +11 sigma)
#define GEMM_UNITS ((N_NODES + 63) / 64)      // 782
#define NBLK 512                              // grid: 2 blocks/CU guaranteed (VGPR<=256)
#define NTHR 256
#define GWAVES (NBLK * 4)                     // 2048 gather waves

typedef __attribute__((ext_vector_type(8))) short bf16x8;
typedef __attribute__((ext_vector_type(4))) float f32x4;

__device__ unsigned g_bar = 0;   // module-load zeroed; monotone across launches (NOT in poisoned ws)

// Device barrier: arrival = ONE device atomicAdd per block; spin = device-scope
// ACQUIRE LOADS (pipeline, no RMW serialization — R8's spin-RMW was the 500us bug).
// Guard bound turns any residual stall into a visible failure, not a hang.
__device__ __forceinline__ void gbarrier() {
    __threadfence();                      // release: drain block's stores to device scope
    __syncthreads();
    if (threadIdx.x == 0) {
        unsigned a = atomicAdd(&g_bar, 1u);              // device-scope arrival
        unsigned target = (a / NBLK + 1u) * NBLK;        // start-value-agnostic
        int guard = 1 << 15;                             // ~0.1 s worst case, then bail visibly
        while (__hip_atomic_load(&g_bar, __ATOMIC_ACQUIRE, __HIP_MEMORY_SCOPE_AGENT) < target
               && --guard) __builtin_amdgcn_s_sleep(64); // ~1.7 us poll interval
    }
    __syncthreads();
    __threadfence();                      // acquire: invalidate stale cached lines
}

__device__ __forceinline__ unsigned pack_bf16x2(float a, float b) {
    unsigned ua = __float_as_uint(a);
    ua = (ua + 0x7FFFu + ((ua >> 16) & 1u)) >> 16;   // RNE
    unsigned ub = __float_as_uint(b);
    ub = (ub + 0x7FFFu + ((ub >> 16) & 1u)) >> 16;
    return ua | (ub << 16);
}

__device__ __forceinline__ unsigned short bf16_1(float a) {
    unsigned u = __float_as_uint(a);
    return (unsigned short)((u + 0x7FFFu + ((u >> 16) & 1u)) >> 16);
}

__device__ __forceinline__ float blo(unsigned u) { return __uint_as_float(u << 16); }
__device__ __forceinline__ float bhi(unsigned u) { return __uint_as_float(u & 0xFFFF0000u); }

__device__ __forceinline__ unsigned pack_f16x2(float a, float b) {
    _Float16 ha = (_Float16)a, hb = (_Float16)b;
    return (unsigned)__builtin_bit_cast(unsigned short, ha) |
           ((unsigned)__builtin_bit_cast(unsigned short, hb) << 16);
}
__device__ __forceinline__ float f16lo(unsigned u) {
    return (float)__builtin_bit_cast(_Float16, (unsigned short)(u & 0xFFFFu));
}
__device__ __forceinline__ float f16hi(unsigned u) {
    return (float)__builtin_bit_cast(_Float16, (unsigned short)(u >> 16));
}

#define ACC8S(v, d) { a[0]+=blo(v.x)*d; a[1]+=bhi(v.x)*d; a[2]+=blo(v.y)*d; a[3]+=bhi(v.y)*d; \
                      a[4]+=blo(v.z)*d; a[5]+=bhi(v.z)*d; a[6]+=blo(v.w)*d; a[7]+=bhi(v.w)*d; }

__device__ __forceinline__ void acc_batch(const uint4* __restrict__ g4, int l, int q,
                                          int sv, float dvv, int nb, float* a) {
    int j0 = 0;
    for (; j0 + 16 <= nb; j0 += 16) {
        int i0 = j0 + q;
        int s0 = __shfl(sv, i0, 64);
        int s1 = __shfl(sv, i0 + 4, 64);
        int s2 = __shfl(sv, i0 + 8, 64);
        int s3 = __shfl(sv, i0 + 12, 64);
        float d0 = __shfl(dvv, i0, 64);
        float d1 = __shfl(dvv, i0 + 4, 64);
        float d2 = __shfl(dvv, i0 + 8, 64);
        float d3 = __shfl(dvv, i0 + 12, 64);
        uint4 v0 = g4[(size_t)s0 * 16 + l];
        uint4 v1 = g4[(size_t)s1 * 16 + l];
        uint4 v2 = g4[(size_t)s2 * 16 + l];
        uint4 v3 = g4[(size_t)s3 * 16 + l];
        ACC8S(v0, d0) ACC8S(v1, d1) ACC8S(v2, d2) ACC8S(v3, d3)
    }
    if (j0 < nb) {
#pragma unroll
        for (int k = 0; k < 4; ++k) {
            int idx = j0 + q + 4 * k;
            int s = __shfl(sv, idx, 64);
            float d = __shfl(dvv, idx, 64);
            if (idx < nb) { uint4 v = g4[(size_t)s * 16 + l]; ACC8S(v, d) }
        }
    }
}

// Single persistent kernel: P1 scat|WTn|zero -> P2 bsort|gemm -> P3 gather+stats -> P4 final.
// Structure identical to R8 (correctness-proven); only barrier + launch bounds changed.
__global__ void __launch_bounds__(NTHR, 2) k_fused(
        const int* __restrict__ erow, const int* __restrict__ ecol,
        const float* __restrict__ x, const float* __restrict__ W,
        const float* __restrict__ gamma, const float* __restrict__ beta,
        float* __restrict__ out,
        unsigned* __restrict__ gbuf, unsigned* __restrict__ aggh,
        unsigned* __restrict__ bEdges, int* __restrict__ bOffsT,
        unsigned* __restrict__ WTn, unsigned short* __restrict__ srcs,
        int2* __restrict__ nodeDesc, float* __restrict__ dinvArr,
        float* __restrict__ sums8) {
    __shared__ __align__(16) unsigned sm[4352];   // 17.4 KB, phase-unioned
    __shared__ int wsum[16];
    __shared__ int wtot;
    const int tid = threadIdx.x, bx = blockIdx.x;
    const int lane = tid & 63, wid = tid >> 6;

    // ================= P1: scat (blocks 0..390) | WTn + sums8 zero (block 391)
    if (bx < A_BLOCKS) {
        int* hist = (int*)sm;   // [NBUCK]
        for (int i = tid; i < NBUCK; i += NTHR) hist[i] = 0;
        __syncthreads();
        const int w = bx, e0 = w * EPB;
        int nE = N_EDGES - e0; if (nE > EPB) nE = EPB;
        int myc[8], myr[8];
#pragma unroll
        for (int k = 0; k < 8; ++k) {
            int idx = tid + (k << 8);
            bool ok = idx < nE;
            myc[k] = ok ? ecol[e0 + idx] : -1;
            myr[k] = ok ? erow[e0 + idx] : 0;
            if (ok) atomicAdd(&hist[myc[k] >> BSHIFT], 1);
        }
        __syncthreads();
        int v0 = hist[tid];
        int v1 = (tid + 256 < NBUCK) ? hist[tid + 256] : 0;
        int s0 = v0, s1 = v1;
#pragma unroll
        for (int d = 1; d < 64; d <<= 1) {
            int u0 = __shfl_up(s0, d, 64);
            int u1 = __shfl_up(s1, d, 64);
            if (lane >= d) { s0 += u0; s1 += u1; }
        }
        if (lane == 63) { wsum[wid] = s0; wsum[4 + wid] = s1; }
        __syncthreads();
        int tot0 = wsum[0] + wsum[1] + wsum[2] + wsum[3];
        int p0 = 0, p1 = tot0;
        for (int i = 0; i < wid; ++i) { p0 += wsum[i]; p1 += wsum[4 + i]; }
        int exc0 = p0 + s0 - v0;
        int exc1 = p1 + s1 - v1;
        bOffsT[tid * A_BLOCKS + w] = exc0;
        if (tid + 256 < NBUCK) bOffsT[(tid + 256) * A_BLOCKS + w] = exc1;
        if (tid == 0) bOffsT[NBUCK * A_BLOCKS + w] = nE;
        hist[tid] = exc0;                                   // cursors
        if (tid + 256 < NBUCK) hist[tid + 256] = exc1;
        __syncthreads();
#pragma unroll
        for (int k = 0; k < 8; ++k) {
            if (myc[k] >= 0) {
                int b = myc[k] >> BSHIFT;
                int r = atomicAdd(&hist[b], 1);  // LDS only
                bEdges[(size_t)w * EPB + r] = (unsigned)myr[k] | ((unsigned)myc[k] << 16);
            }
        }
    } else if (bx == A_BLOCKS) {
        // WTn dword i = ((nt*4+kt)*64 + q*16+m)*4 + j  holds
        //   pack( W[kt*32+q*8+2j][nt*16+m], W[kt*32+q*8+2j+1][nt*16+m] )
#pragma unroll
        for (int it = 0; it < 32; ++it) {
            int i = tid + (it << 8);
            int j = i & 3, l = (i >> 2) & 63, kt = (i >> 8) & 3, nt = i >> 10;
            int m = l & 15, q = l >> 4;
            int kr = kt * 32 + q * 8 + 2 * j;
            int n = nt * 16 + m;
            WTn[i] = pack_bf16x2(W[kr * C + n], W[(kr + 1) * C + n]);
        }
        for (int i = tid; i < 2048; i += NTHR) sums8[i] = 0.f;
    }
    gbarrier();

    // ================= P2: bsort (units 0..390) | gemm (units 391..1172)
    for (int u = bx; u < A_BLOCKS + GEMM_UNITS; u += NBLK) {
        if (u < NBUCK) {
            const int b = u;
            int* sS = (int*)sm;                        // [391]
            int* sO = (int*)sm + 392;                  // [392]
            unsigned* ebuf = sm + 792;                 // [EBUF]
            int* h = (int*)(sm + 792 + EBUF);          // [128]
            int i1 = tid + 256;
            int st0 = bOffsT[b * A_BLOCKS + tid];
            int v0 = bOffsT[(b + 1) * A_BLOCKS + tid] - st0;
            int st1 = 0, v1 = 0;
            if (i1 < A_BLOCKS) {
                st1 = bOffsT[b * A_BLOCKS + i1];
                v1 = bOffsT[(b + 1) * A_BLOCKS + i1] - st1;
            }
            sS[tid] = st0;
            if (i1 < A_BLOCKS) sS[i1] = st1;
            if (tid < 128) h[tid] = 0;
            int ep = st0 + st1;
            int s0 = v0, s1 = v1;
#pragma unroll
            for (int d = 1; d < 64; d <<= 1) {
                int u0 = __shfl_up(s0, d, 64);
                int u1 = __shfl_up(s1, d, 64);
                if (lane >= d) { s0 += u0; s1 += u1; }
                ep += __shfl_xor(ep, d, 64);
            }
            if (lane == 63) { wsum[wid] = s0; wsum[4 + wid] = s1; }
            if (lane == 0) wsum[8 + wid] = ep;
            __syncthreads();
            int tot0 = wsum[0] + wsum[1] + wsum[2] + wsum[3];
            int tot1 = wsum[4] + wsum[5] + wsum[6] + wsum[7];
            int e0 = wsum[8] + wsum[9] + wsum[10] + wsum[11];
            int p0 = 0, p1 = tot0;
            for (int i = 0; i < wid; ++i) { p0 += wsum[i]; p1 += wsum[4 + i]; }
            sO[tid] = p0 + s0 - v0;
            if (i1 < A_BLOCKS) sO[i1] = p1 + s1 - v1;
            if (tid == 0) sO[A_BLOCKS] = tot0 + tot1;
            __syncthreads();
            int c = sO[A_BLOCKS];
            if (c > EBUF) c = EBUF;  // statistically impossible; memory-safety only
            for (int seg = tid; seg < A_BLOCKS; seg += NTHR) {
                int o = sO[seg];
                int n = sO[seg + 1] - o;
                const unsigned* srcp = bEdges + (size_t)seg * EPB + sS[seg];
                for (int k = 0; k < n; ++k) {
                    int dp = o + k;
                    if (dp < EBUF) ebuf[dp] = srcp[k];
                }
            }
            __syncthreads();
            int n0 = b << BSHIFT;
            int nn = N_NODES - n0; if (nn > 128) nn = 128;
            for (int e = tid; e < c; e += NTHR)
                atomicAdd(&h[(int)(ebuf[e] >> 16) - n0], 1);
            __syncthreads();
            int v = 0, sc = 0;
            if (tid < 128) {
                int ln = tid & 63;
                v = h[tid];
                sc = v;
#pragma unroll
                for (int d = 1; d < 64; d <<= 1) {
                    int uu = __shfl_up(sc, d, 64);
                    if (ln >= d) sc += uu;
                }
                if (tid == 63) wtot = sc;
            }
            __syncthreads();
            if (tid < 128) {
                int ex = sc - v + ((tid >= 64) ? wtot : 0);
                if (tid < nn) {
                    nodeDesc[n0 + tid] = make_int2(e0 + ex, v);   // {beg, deg}
                    dinvArr[n0 + tid] = rsqrtf((float)v + 1.f);
                }
                h[tid] = ex;  // cursor
            }
            __syncthreads();
            for (int e = tid; e < c; e += NTHR) {
                unsigned pe = ebuf[e];
                int r = atomicAdd(&h[(int)(pe >> 16) - n0], 1);
                srcs[e0 + r] = (unsigned short)(pe & 0xFFFFu);
            }
        } else {
            // ---- gemm unit: 64 rows, unscaled g = bf16(x@W) ----
            unsigned* xs = sm;  // [64*68]
            int r0 = (u - NBUCK) * 64;
            const float4* x4 = (const float4*)x;
#pragma unroll
            for (int it = 0; it < 8; ++it) {
                int i = tid + (it << 8);
                int r = i >> 5, c4 = i & 31;
                float4 v = {0.f, 0.f, 0.f, 0.f};
                if (r0 + r < N_NODES) v = x4[(size_t)(r0 + r) * 32 + c4];
                xs[r * 68 + c4 * 2]     = pack_bf16x2(v.x, v.y);
                xs[r * 68 + c4 * 2 + 1] = pack_bf16x2(v.z, v.w);
            }
            __syncthreads();
            int r0w = r0 + wid * 16;
            if (r0w < N_NODES) {
                int m = lane & 15, q = lane >> 4;
                bf16x8 afrag[4];
#pragma unroll
                for (int kt = 0; kt < 4; ++kt)
                    afrag[kt] = *(const bf16x8*)&xs[(wid * 16 + m) * 68 + kt * 16 + q * 4];
                const uint4* B4 = (const uint4*)WTn;
                f32x4 acc[8];
#pragma unroll
                for (int nt = 0; nt < 8; ++nt)
                    acc[nt][0] = acc[nt][1] = acc[nt][2] = acc[nt][3] = 0.f;
#pragma unroll
                for (int nt = 0; nt < 8; ++nt) {
#pragma unroll
                    for (int kt = 0; kt < 4; ++kt) {
                        uint4 braw = B4[(nt * 4 + kt) * 64 + lane];   // coalesced
                        bf16x8 bfrag = __builtin_bit_cast(bf16x8, braw);
                        acc[nt] = __builtin_amdgcn_mfma_f32_16x16x32_bf16(afrag[kt], bfrag, acc[nt], 0, 0, 0);
                    }
                }
                unsigned short* g16 = (unsigned short*)gbuf;
                int rb = r0w + q * 4;
#pragma unroll
                for (int nt = 0; nt < 8; ++nt) {
                    int cbase = nt * 16 + m;
#pragma unroll
                    for (int reg = 0; reg < 4; ++reg)
                        g16[(size_t)(rb + reg) * C + cbase] = bf16_1(acc[nt][reg]);
                }
            }
        }
        __syncthreads();   // LDS handoff between grid-strided units
    }
    gbarrier();

    // ================= P3: gather + fused BN stats
    {
        float* lsA = (float*)sm;          // [4][128]
        float* lsQ = lsA + 512;           // [4][128]
        const uint4* g4 = (const uint4*)gbuf;
        const int l = lane & 15, q = lane >> 4;
        float sA[4] = {0.f, 0.f, 0.f, 0.f}, sQ[4] = {0.f, 0.f, 0.f, 0.f};
        for (int node = bx * 4 + wid; node < N_NODES; node += GWAVES) {
            int2 d = nodeDesc[node];
            int beg = d.x, deg = d.y;
            float dt = rsqrtf((float)deg + 1.f);
            float a[8];
            if (q == 0) {
                uint4 u = g4[(size_t)node * 16 + l];  // self-loop: *dt here, *dt again at end
                a[0]=blo(u.x)*dt; a[1]=bhi(u.x)*dt; a[2]=blo(u.y)*dt; a[3]=bhi(u.y)*dt;
                a[4]=blo(u.z)*dt; a[5]=bhi(u.z)*dt; a[6]=blo(u.w)*dt; a[7]=bhi(u.w)*dt;
            } else {
#pragma unroll
                for (int i = 0; i < 8; ++i) a[i] = 0.f;
            }
            for (int base = beg; base < beg + deg; base += 64) {
                int nb = beg + deg - base; if (nb > 64) nb = 64;
                int sv = 0; float dvv = 0.f;
                if (lane < nb) { sv = srcs[base + lane]; dvv = dinvArr[sv]; }
                acc_batch(g4, l, q, sv, dvv, nb, a);
            }
#pragma unroll
            for (int i = 0; i < 8; ++i) {
                a[i] += __shfl_xor(a[i], 16, 64);
                a[i] += __shfl_xor(a[i], 32, 64);
            }
            if (q < 2) {
                float f0 = a[q * 4 + 0] * dt, f1 = a[q * 4 + 1] * dt;
                float f2 = a[q * 4 + 2] * dt, f3 = a[q * 4 + 3] * dt;
                sA[0] += f0; sQ[0] += f0 * f0;
                sA[1] += f1; sQ[1] += f1 * f1;
                sA[2] += f2; sQ[2] += f2 * f2;
                sA[3] += f3; sQ[3] += f3 * f3;
                uint2 pv; pv.x = pack_f16x2(f0, f1); pv.y = pack_f16x2(f2, f3);
                *(uint2*)(aggh + (size_t)node * 64 + l * 4 + q * 2) = pv;
            }
        }
        if (q < 2) {
#pragma unroll
            for (int i = 0; i < 4; ++i) {
                lsA[wid * 128 + (l * 2 + q) * 4 + i] = sA[i];   // slot == channel
                lsQ[wid * 128 + (l * 2 + q) * 4 + i] = sQ[i];
            }
        }
        __syncthreads();
        if (tid < 128) {
            float s = 0.f, sq = 0.f;
#pragma unroll
            for (int wd = 0; wd < 4; ++wd) {
                s  += lsA[wd * 128 + tid];
                sq += lsQ[wd * 128 + tid];
            }
            int slice = (bx & 7) * 256;
            atomicAdd(&sums8[slice + tid], s);
            atomicAdd(&sums8[slice + 128 + tid], sq);
        }
    }
    gbarrier();

    // ================= P4: final  y = relu(aggh*scale + shift)
    {
        float* scs = (float*)sm;
        float* shs = scs + 128;
        if (tid < C) {
            float s = 0.f, sq = 0.f;
#pragma unroll
            for (int k = 0; k < 8; ++k) {
                s  += sums8[k * 256 + tid];
                sq += sums8[k * 256 + 128 + tid];
            }
            float mean = s * (1.0f / N_NODES);
            float var = sq * (1.0f / N_NODES) - mean * mean;
            float sc = gamma[tid] * rsqrtf(var + BN_EPS);
            scs[tid] = sc;
            shs[tid] = beta[tid] - mean * sc;
        }
        __syncthreads();
        const uint4* a4 = (const uint4*)aggh;
        for (int i = bx * NTHR + tid; i < N_NODES * 16; i += NBLK * NTHR) {
            uint4 v = a4[i];
            int c = (i & 15) * 8;
            float4 o0, o1;
            o0.x = fmaxf(f16lo(v.x) * scs[c+0] + shs[c+0], 0.f);
            o0.y = fmaxf(f16hi(v.x) * scs[c+1] + shs[c+1], 0.f);
            o0.z = fmaxf(f16lo(v.y) * scs[c+2] + shs[c+2], 0.f);
            o0.w = fmaxf(f16hi(v.y) * scs[c+3] + shs[c+3], 0.f);
            o1.x = fmaxf(f16lo(v.z) * scs[c+4] + shs[c+4], 0.f);
            o1.y = fmaxf(f16hi(v.z) * scs[c+5] + shs[c+5], 0.f);
            o1.z = fmaxf(f16lo(v.w) * scs[c+6] + shs[c+6], 0.f);
            o1.w = fmaxf(f16hi(v.w) * scs[c+7] + shs[c+7], 0.f);
            float4* o = (float4*)(out + (size_t)i * 8);
            o[0] = o0; o[1] = o1;
        }
    }
}

extern "C" void kernel_launch(void* const* d_in, const int* in_sizes, int n_in,
                              void* d_out, int out_size, void* d_ws, size_t ws_size,
                              hipStream_t stream) {
    const float* x     = (const float*)d_in[0];
    const float* W     = (const float*)d_in[1];
    // d_in[2] = bias: cancels in BatchNorm, unused
    const float* gamma = (const float*)d_in[3];
    const float* beta  = (const float*)d_in[4];
    const int*   eidx  = (const int*)d_in[5];
    const int* erow = eidx;
    const int* ecol = eidx + N_EDGES;

    float* out = (float*)d_out;  // [N, C] f32

    // workspace layout (16B-aligned slabs)
    unsigned* gbuf   = (unsigned*)d_ws;                          // [N*64] bf16x2 rows (12.8 MB)
    unsigned* aggh   = gbuf + (size_t)N_NODES * 64;              // [N*64] f16x2 rows (12.8 MB)
    unsigned* bEdges = aggh + (size_t)N_NODES * 64;              // [A_BLOCKS*EPB] (3.2 MB)
    unsigned* WTn    = bEdges + (size_t)A_BLOCKS * EPB;          // [8192] bf16x2 (W, MFMA-B layout)
    unsigned short* srcs = (unsigned short*)(WTn + 8192);        // [E] u16 (1.6 MB)
    int2*  nodeDesc = (int2*)(srcs + N_EDGES);                   // [N] {beg, deg}
    float* dinvArr  = (float*)(nodeDesc + N_NODES);              // [N]
    float* sums8    = dinvArr + N_NODES;                         // [8*256] sliced BN accum
    int*   bOffsT   = (int*)(sums8 + 2048);                      // [(NBUCK+1)*A_BLOCKS]

    k_fused<<<NBLK, NTHR, 0, stream>>>(erow, ecol, x, W, gamma, beta, out,
                                       gbuf, aggh, bEdges, bOffsT, WTn, srcs,
                                       nodeDesc, dinvArr, sums8);
}

// Round 10
// 544.630 us; speedup vs baseline: 1.1290x; 1.1290x over previous
//
#include <hip/hip_runtime.h>

#define N_NODES 50000
#define N_EDGES 800000
#define C 128
#define BN_EPS 1e-5f
#define BSHIFT 7                              // 128 nodes per bucket
#define NBUCK ((N_NODES + 127) >> BSHIFT)     // 391
#define EPB 2048                              // edges per scat unit
#define A_BLOCKS ((N_EDGES + EPB - 1) / EPB)  // 391
#define EBUF 2560                             // per-bucket staging cap (mean 2046, +11 sigma)
#define GEMM_UNITS ((N_NODES + 63) / 64)      // 782
#define NBLK 512                              // grid: 2 blocks/CU guaranteed (VGPR<=256)
#define NTHR 256
#define GWAVES (NBLK * 4)                     // 2048 gather waves

typedef __attribute__((ext_vector_type(8))) short bf16x8;
typedef __attribute__((ext_vector_type(4))) float f32x4;

__device__ unsigned g_bar = 0;   // module-load zeroed; monotone across launches (NOT in poisoned ws)

// Device barrier. R8 failed (spin-RMW), R9 failed (spin-ACQUIRE: each poll
// emits buffer_inv -> grid-wide cache-invalidation storm, FETCH 3x, all idle).
// Fix: spin on a RELAXED agent-scope load (plain coherence-point read, no
// invalidate); acquire semantics applied ONCE after the spin via threadfence.
__device__ __forceinline__ void gbarrier() {
    __threadfence();                      // release: drain this block's stores
    __syncthreads();
    if (threadIdx.x == 0) {
        unsigned a = atomicAdd(&g_bar, 1u);              // device-scope arrival (relaxed)
        unsigned target = (a / NBLK + 1u) * NBLK;        // start-value-agnostic
        int guard = 1 << 15;                             // bounded: fail visibly, never hang
        while (__hip_atomic_load(&g_bar, __ATOMIC_RELAXED, __HIP_MEMORY_SCOPE_AGENT) < target
               && --guard) __builtin_amdgcn_s_sleep(64); // ~1.7 us poll, no cache ops
    }
    __syncthreads();
    __threadfence();                      // acquire ONCE: invalidate stale lines
}

__device__ __forceinline__ unsigned pack_bf16x2(float a, float b) {
    unsigned ua = __float_as_uint(a);
    ua = (ua + 0x7FFFu + ((ua >> 16) & 1u)) >> 16;   // RNE
    unsigned ub = __float_as_uint(b);
    ub = (ub + 0x7FFFu + ((ub >> 16) & 1u)) >> 16;
    return ua | (ub << 16);
}

__device__ __forceinline__ unsigned short bf16_1(float a) {
    unsigned u = __float_as_uint(a);
    return (unsigned short)((u + 0x7FFFu + ((u >> 16) & 1u)) >> 16);
}

__device__ __forceinline__ float blo(unsigned u) { return __uint_as_float(u << 16); }
__device__ __forceinline__ float bhi(unsigned u) { return __uint_as_float(u & 0xFFFF0000u); }

__device__ __forceinline__ unsigned pack_f16x2(float a, float b) {
    _Float16 ha = (_Float16)a, hb = (_Float16)b;
    return (unsigned)__builtin_bit_cast(unsigned short, ha) |
           ((unsigned)__builtin_bit_cast(unsigned short, hb) << 16);
}
__device__ __forceinline__ float f16lo(unsigned u) {
    return (float)__builtin_bit_cast(_Float16, (unsigned short)(u & 0xFFFFu));
}
__device__ __forceinline__ float f16hi(unsigned u) {
    return (float)__builtin_bit_cast(_Float16, (unsigned short)(u >> 16));
}

#define ACC8S(v, d) { a[0]+=blo(v.x)*d; a[1]+=bhi(v.x)*d; a[2]+=blo(v.y)*d; a[3]+=bhi(v.y)*d; \
                      a[4]+=blo(v.z)*d; a[5]+=bhi(v.z)*d; a[6]+=blo(v.w)*d; a[7]+=bhi(v.w)*d; }

__device__ __forceinline__ void acc_batch(const uint4* __restrict__ g4, int l, int q,
                                          int sv, float dvv, int nb, float* a) {
    int j0 = 0;
    for (; j0 + 16 <= nb; j0 += 16) {
        int i0 = j0 + q;
        int s0 = __shfl(sv, i0, 64);
        int s1 = __shfl(sv, i0 + 4, 64);
        int s2 = __shfl(sv, i0 + 8, 64);
        int s3 = __shfl(sv, i0 + 12, 64);
        float d0 = __shfl(dvv, i0, 64);
        float d1 = __shfl(dvv, i0 + 4, 64);
        float d2 = __shfl(dvv, i0 + 8, 64);
        float d3 = __shfl(dvv, i0 + 12, 64);
        uint4 v0 = g4[(size_t)s0 * 16 + l];
        uint4 v1 = g4[(size_t)s1 * 16 + l];
        uint4 v2 = g4[(size_t)s2 * 16 + l];
        uint4 v3 = g4[(size_t)s3 * 16 + l];
        ACC8S(v0, d0) ACC8S(v1, d1) ACC8S(v2, d2) ACC8S(v3, d3)
    }
    if (j0 < nb) {
#pragma unroll
        for (int k = 0; k < 4; ++k) {
            int idx = j0 + q + 4 * k;
            int s = __shfl(sv, idx, 64);
            float d = __shfl(dvv, idx, 64);
            if (idx < nb) { uint4 v = g4[(size_t)s * 16 + l]; ACC8S(v, d) }
        }
    }
}

// Single persistent kernel: P1 scat|WTn|zero -> P2 bsort|gemm -> P3 gather+stats -> P4 final.
// Structure identical to R8/R9 (correctness-proven twice); only the spin changed.
__global__ void __launch_bounds__(NTHR, 2) k_fused(
        const int* __restrict__ erow, const int* __restrict__ ecol,
        const float* __restrict__ x, const float* __restrict__ W,
        const float* __restrict__ gamma, const float* __restrict__ beta,
        float* __restrict__ out,
        unsigned* __restrict__ gbuf, unsigned* __restrict__ aggh,
        unsigned* __restrict__ bEdges, int* __restrict__ bOffsT,
        unsigned* __restrict__ WTn, unsigned short* __restrict__ srcs,
        int2* __restrict__ nodeDesc, float* __restrict__ dinvArr,
        float* __restrict__ sums8) {
    __shared__ __align__(16) unsigned sm[4352];   // 17.4 KB, phase-unioned
    __shared__ int wsum[16];
    __shared__ int wtot;
    const int tid = threadIdx.x, bx = blockIdx.x;
    const int lane = tid & 63, wid = tid >> 6;

    // ================= P1: scat (blocks 0..390) | WTn + sums8 zero (block 391)
    if (bx < A_BLOCKS) {
        int* hist = (int*)sm;   // [NBUCK]
        for (int i = tid; i < NBUCK; i += NTHR) hist[i] = 0;
        __syncthreads();
        const int w = bx, e0 = w * EPB;
        int nE = N_EDGES - e0; if (nE > EPB) nE = EPB;
        int myc[8], myr[8];
#pragma unroll
        for (int k = 0; k < 8; ++k) {
            int idx = tid + (k << 8);
            bool ok = idx < nE;
            myc[k] = ok ? ecol[e0 + idx] : -1;
            myr[k] = ok ? erow[e0 + idx] : 0;
            if (ok) atomicAdd(&hist[myc[k] >> BSHIFT], 1);
        }
        __syncthreads();
        int v0 = hist[tid];
        int v1 = (tid + 256 < NBUCK) ? hist[tid + 256] : 0;
        int s0 = v0, s1 = v1;
#pragma unroll
        for (int d = 1; d < 64; d <<= 1) {
            int u0 = __shfl_up(s0, d, 64);
            int u1 = __shfl_up(s1, d, 64);
            if (lane >= d) { s0 += u0; s1 += u1; }
        }
        if (lane == 63) { wsum[wid] = s0; wsum[4 + wid] = s1; }
        __syncthreads();
        int tot0 = wsum[0] + wsum[1] + wsum[2] + wsum[3];
        int p0 = 0, p1 = tot0;
        for (int i = 0; i < wid; ++i) { p0 += wsum[i]; p1 += wsum[4 + i]; }
        int exc0 = p0 + s0 - v0;
        int exc1 = p1 + s1 - v1;
        bOffsT[tid * A_BLOCKS + w] = exc0;
        if (tid + 256 < NBUCK) bOffsT[(tid + 256) * A_BLOCKS + w] = exc1;
        if (tid == 0) bOffsT[NBUCK * A_BLOCKS + w] = nE;
        hist[tid] = exc0;                                   // cursors
        if (tid + 256 < NBUCK) hist[tid + 256] = exc1;
        __syncthreads();
#pragma unroll
        for (int k = 0; k < 8; ++k) {
            if (myc[k] >= 0) {
                int b = myc[k] >> BSHIFT;
                int r = atomicAdd(&hist[b], 1);  // LDS only
                bEdges[(size_t)w * EPB + r] = (unsigned)myr[k] | ((unsigned)myc[k] << 16);
            }
        }
    } else if (bx == A_BLOCKS) {
        // WTn dword i = ((nt*4+kt)*64 + q*16+m)*4 + j  holds
        //   pack( W[kt*32+q*8+2j][nt*16+m], W[kt*32+q*8+2j+1][nt*16+m] )
#pragma unroll
        for (int it = 0; it < 32; ++it) {
            int i = tid + (it << 8);
            int j = i & 3, l = (i >> 2) & 63, kt = (i >> 8) & 3, nt = i >> 10;
            int m = l & 15, q = l >> 4;
            int kr = kt * 32 + q * 8 + 2 * j;
            int n = nt * 16 + m;
            WTn[i] = pack_bf16x2(W[kr * C + n], W[(kr + 1) * C + n]);
        }
        for (int i = tid; i < 2048; i += NTHR) sums8[i] = 0.f;
    }
    gbarrier();

    // ================= P2: bsort (units 0..390) | gemm (units 391..1172)
    for (int u = bx; u < A_BLOCKS + GEMM_UNITS; u += NBLK) {
        if (u < NBUCK) {
            const int b = u;
            int* sS = (int*)sm;                        // [391]
            int* sO = (int*)sm + 392;                  // [392]
            unsigned* ebuf = sm + 792;                 // [EBUF]
            int* h = (int*)(sm + 792 + EBUF);          // [128]
            int i1 = tid + 256;
            int st0 = bOffsT[b * A_BLOCKS + tid];
            int v0 = bOffsT[(b + 1) * A_BLOCKS + tid] - st0;
            int st1 = 0, v1 = 0;
            if (i1 < A_BLOCKS) {
                st1 = bOffsT[b * A_BLOCKS + i1];
                v1 = bOffsT[(b + 1) * A_BLOCKS + i1] - st1;
            }
            sS[tid] = st0;
            if (i1 < A_BLOCKS) sS[i1] = st1;
            if (tid < 128) h[tid] = 0;
            int ep = st0 + st1;
            int s0 = v0, s1 = v1;
#pragma unroll
            for (int d = 1; d < 64; d <<= 1) {
                int u0 = __shfl_up(s0, d, 64);
                int u1 = __shfl_up(s1, d, 64);
                if (lane >= d) { s0 += u0; s1 += u1; }
                ep += __shfl_xor(ep, d, 64);
            }
            if (lane == 63) { wsum[wid] = s0; wsum[4 + wid] = s1; }
            if (lane == 0) wsum[8 + wid] = ep;
            __syncthreads();
            int tot0 = wsum[0] + wsum[1] + wsum[2] + wsum[3];
            int tot1 = wsum[4] + wsum[5] + wsum[6] + wsum[7];
            int e0 = wsum[8] + wsum[9] + wsum[10] + wsum[11];
            int p0 = 0, p1 = tot0;
            for (int i = 0; i < wid; ++i) { p0 += wsum[i]; p1 += wsum[4 + i]; }
            sO[tid] = p0 + s0 - v0;
            if (i1 < A_BLOCKS) sO[i1] = p1 + s1 - v1;
            if (tid == 0) sO[A_BLOCKS] = tot0 + tot1;
            __syncthreads();
            int c = sO[A_BLOCKS];
            if (c > EBUF) c = EBUF;  // statistically impossible; memory-safety only
            for (int seg = tid; seg < A_BLOCKS; seg += NTHR) {
                int o = sO[seg];
                int n = sO[seg + 1] - o;
                const unsigned* srcp = bEdges + (size_t)seg * EPB + sS[seg];
                for (int k = 0; k < n; ++k) {
                    int dp = o + k;
                    if (dp < EBUF) ebuf[dp] = srcp[k];
                }
            }
            __syncthreads();
            int n0 = b << BSHIFT;
            int nn = N_NODES - n0; if (nn > 128) nn = 128;
            for (int e = tid; e < c; e += NTHR)
                atomicAdd(&h[(int)(ebuf[e] >> 16) - n0], 1);
            __syncthreads();
            int v = 0, sc = 0;
            if (tid < 128) {
                int ln = tid & 63;
                v = h[tid];
                sc = v;
#pragma unroll
                for (int d = 1; d < 64; d <<= 1) {
                    int uu = __shfl_up(sc, d, 64);
                    if (ln >= d) sc += uu;
                }
                if (tid == 63) wtot = sc;
            }
            __syncthreads();
            if (tid < 128) {
                int ex = sc - v + ((tid >= 64) ? wtot : 0);
                if (tid < nn) {
                    nodeDesc[n0 + tid] = make_int2(e0 + ex, v);   // {beg, deg}
                    dinvArr[n0 + tid] = rsqrtf((float)v + 1.f);
                }
                h[tid] = ex;  // cursor
            }
            __syncthreads();
            for (int e = tid; e < c; e += NTHR) {
                unsigned pe = ebuf[e];
                int r = atomicAdd(&h[(int)(pe >> 16) - n0], 1);
                srcs[e0 + r] = (unsigned short)(pe & 0xFFFFu);
            }
        } else {
            // ---- gemm unit: 64 rows, unscaled g = bf16(x@W) ----
            unsigned* xs = sm;  // [64*68]
            int r0 = (u - NBUCK) * 64;
            const float4* x4 = (const float4*)x;
#pragma unroll
            for (int it = 0; it < 8; ++it) {
                int i = tid + (it << 8);
                int r = i >> 5, c4 = i & 31;
                float4 v = {0.f, 0.f, 0.f, 0.f};
                if (r0 + r < N_NODES) v = x4[(size_t)(r0 + r) * 32 + c4];
                xs[r * 68 + c4 * 2]     = pack_bf16x2(v.x, v.y);
                xs[r * 68 + c4 * 2 + 1] = pack_bf16x2(v.z, v.w);
            }
            __syncthreads();
            int r0w = r0 + wid * 16;
            if (r0w < N_NODES) {
                int m = lane & 15, q = lane >> 4;
                bf16x8 afrag[4];
#pragma unroll
                for (int kt = 0; kt < 4; ++kt)
                    afrag[kt] = *(const bf16x8*)&xs[(wid * 16 + m) * 68 + kt * 16 + q * 4];
                const uint4* B4 = (const uint4*)WTn;
                f32x4 acc[8];
#pragma unroll
                for (int nt = 0; nt < 8; ++nt)
                    acc[nt][0] = acc[nt][1] = acc[nt][2] = acc[nt][3] = 0.f;
#pragma unroll
                for (int nt = 0; nt < 8; ++nt) {
#pragma unroll
                    for (int kt = 0; kt < 4; ++kt) {
                        uint4 braw = B4[(nt * 4 + kt) * 64 + lane];   // coalesced
                        bf16x8 bfrag = __builtin_bit_cast(bf16x8, braw);
                        acc[nt] = __builtin_amdgcn_mfma_f32_16x16x32_bf16(afrag[kt], bfrag, acc[nt], 0, 0, 0);
                    }
                }
                unsigned short* g16 = (unsigned short*)gbuf;
                int rb = r0w + q * 4;
#pragma unroll
                for (int nt = 0; nt < 8; ++nt) {
                    int cbase = nt * 16 + m;
#pragma unroll
                    for (int reg = 0; reg < 4; ++reg)
                        g16[(size_t)(rb + reg) * C + cbase] = bf16_1(acc[nt][reg]);
                }
            }
        }
        __syncthreads();   // LDS handoff between grid-strided units
    }
    gbarrier();

    // ================= P3: gather + fused BN stats
    {
        float* lsA = (float*)sm;          // [4][128]
        float* lsQ = lsA + 512;           // [4][128]
        const uint4* g4 = (const uint4*)gbuf;
        const int l = lane & 15, q = lane >> 4;
        float sA[4] = {0.f, 0.f, 0.f, 0.f}, sQ[4] = {0.f, 0.f, 0.f, 0.f};
        for (int node = bx * 4 + wid; node < N_NODES; node += GWAVES) {
            int2 d = nodeDesc[node];
            int beg = d.x, deg = d.y;
            float dt = rsqrtf((float)deg + 1.f);
            float a[8];
            if (q == 0) {
                uint4 u = g4[(size_t)node * 16 + l];  // self-loop: *dt here, *dt again at end
                a[0]=blo(u.x)*dt; a[1]=bhi(u.x)*dt; a[2]=blo(u.y)*dt; a[3]=bhi(u.y)*dt;
                a[4]=blo(u.z)*dt; a[5]=bhi(u.z)*dt; a[6]=blo(u.w)*dt; a[7]=bhi(u.w)*dt;
            } else {
#pragma unroll
                for (int i = 0; i < 8; ++i) a[i] = 0.f;
            }
            for (int base = beg; base < beg + deg; base += 64) {
                int nb = beg + deg - base; if (nb > 64) nb = 64;
                int sv = 0; float dvv = 0.f;
                if (lane < nb) { sv = srcs[base + lane]; dvv = dinvArr[sv]; }
                acc_batch(g4, l, q, sv, dvv, nb, a);
            }
#pragma unroll
            for (int i = 0; i < 8; ++i) {
                a[i] += __shfl_xor(a[i], 16, 64);
                a[i] += __shfl_xor(a[i], 32, 64);
            }
            if (q < 2) {
                float f0 = a[q * 4 + 0] * dt, f1 = a[q * 4 + 1] * dt;
                float f2 = a[q * 4 + 2] * dt, f3 = a[q * 4 + 3] * dt;
                sA[0] += f0; sQ[0] += f0 * f0;
                sA[1] += f1; sQ[1] += f1 * f1;
                sA[2] += f2; sQ[2] += f2 * f2;
                sA[3] += f3; sQ[3] += f3 * f3;
                uint2 pv; pv.x = pack_f16x2(f0, f1); pv.y = pack_f16x2(f2, f3);
                *(uint2*)(aggh + (size_t)node * 64 + l * 4 + q * 2) = pv;
            }
        }
        if (q < 2) {
#pragma unroll
            for (int i = 0; i < 4; ++i) {
                lsA[wid * 128 + (l * 2 + q) * 4 + i] = sA[i];   // slot == channel
                lsQ[wid * 128 + (l * 2 + q) * 4 + i] = sQ[i];
            }
        }
        __syncthreads();
        if (tid < 128) {
            float s = 0.f, sq = 0.f;
#pragma unroll
            for (int wd = 0; wd < 4; ++wd) {
                s  += lsA[wd * 128 + tid];
                sq += lsQ[wd * 128 + tid];
            }
            int slice = (bx & 7) * 256;
            atomicAdd(&sums8[slice + tid], s);
            atomicAdd(&sums8[slice + 128 + tid], sq);
        }
    }
    gbarrier();

    // ================= P4: final  y = relu(aggh*scale + shift)
    {
        float* scs = (float*)sm;
        float* shs = scs + 128;
        if (tid < C) {
            float s = 0.f, sq = 0.f;
#pragma unroll
            for (int k = 0; k < 8; ++k) {
                s  += sums8[k * 256 + tid];
                sq += sums8[k * 256 + 128 + tid];
            }
            float mean = s * (1.0f / N_NODES);
            float var = sq * (1.0f / N_NODES) - mean * mean;
            float sc = gamma[tid] * rsqrtf(var + BN_EPS);
            scs[tid] = sc;
            shs[tid] = beta[tid] - mean * sc;
        }
        __syncthreads();
        const uint4* a4 = (const uint4*)aggh;
        for (int i = bx * NTHR + tid; i < N_NODES * 16; i += NBLK * NTHR) {
            uint4 v = a4[i];
            int c = (i & 15) * 8;
            float4 o0, o1;
            o0.x = fmaxf(f16lo(v.x) * scs[c+0] + shs[c+0], 0.f);
            o0.y = fmaxf(f16hi(v.x) * scs[c+1] + shs[c+1], 0.f);
            o0.z = fmaxf(f16lo(v.y) * scs[c+2] + shs[c+2], 0.f);
            o0.w = fmaxf(f16hi(v.y) * scs[c+3] + shs[c+3], 0.f);
            o1.x = fmaxf(f16lo(v.z) * scs[c+4] + shs[c+4], 0.f);
            o1.y = fmaxf(f16hi(v.z) * scs[c+5] + shs[c+5], 0.f);
            o1.z = fmaxf(f16lo(v.w) * scs[c+6] + shs[c+6], 0.f);
            o1.w = fmaxf(f16hi(v.w) * scs[c+7] + shs[c+7], 0.f);
            float4* o = (float4*)(out + (size_t)i * 8);
            o[0] = o0; o[1] = o1;
        }
    }
}

extern "C" void kernel_launch(void* const* d_in, const int* in_sizes, int n_in,
                              void* d_out, int out_size, void* d_ws, size_t ws_size,
                              hipStream_t stream) {
    const float* x     = (const float*)d_in[0];
    const float* W     = (const float*)d_in[1];
    // d_in[2] = bias: cancels in BatchNorm, unused
    const float* gamma = (const float*)d_in[3];
    const float* beta  = (const float*)d_in[4];
    const int*   eidx  = (const int*)d_in[5];
    const int* erow = eidx;
    const int* ecol = eidx + N_EDGES;

    float* out = (float*)d_out;  // [N, C] f32

    // workspace layout (16B-aligned slabs)
    unsigned* gbuf   = (unsigned*)d_ws;                          // [N*64] bf16x2 rows (12.8 MB)
    unsigned* aggh   = gbuf + (size_t)N_NODES * 64;              // [N*64] f16x2 rows (12.8 MB)
    unsigned* bEdges = aggh + (size_t)N_NODES * 64;              // [A_BLOCKS*EPB] (3.2 MB)
    unsigned* WTn    = bEdges + (size_t)A_BLOCKS * EPB;          // [8192] bf16x2 (W, MFMA-B layout)
    unsigned short* srcs = (unsigned short*)(WTn + 8192);        // [E] u16 (1.6 MB)
    int2*  nodeDesc = (int2*)(srcs + N_EDGES);                   // [N] {beg, deg}
    float* dinvArr  = (float*)(nodeDesc + N_NODES);              // [N]
    float* sums8    = dinvArr + N_NODES;                         // [8*256] sliced BN accum
    int*   bOffsT   = (int*)(sums8 + 2048);                      // [(NBUCK+1)*A_BLOCKS]

    k_fused<<<NBLK, NTHR, 0, stream>>>(erow, ecol, x, W, gamma, beta, out,
                                       gbuf, aggh, bEdges, bOffsT, WTn, srcs,
                                       nodeDesc, dinvArr, sums8);
}

// Round 11
// 152.739 us; speedup vs baseline: 4.0259x; 3.5658x over previous
//
#include <hip/hip_runtime.h>

#define N_NODES 50000
#define N_EDGES 800000
#define C 128
#define BN_EPS 1e-5f
#define BSHIFT 7                              // 128 nodes per bucket
#define NBUCK ((N_NODES + 127) >> BSHIFT)     // 391
#define EPB 2048                              // edges per scat block
#define A_BLOCKS ((N_EDGES + EPB - 1) / EPB)  // 391
#define EBUF 2560                             // per-bucket staging cap (mean 2046, +11 sigma)
#define GEMM_BLOCKS ((N_NODES + 63) / 64)     // 782
#define GATHER_BLOCKS 512
#define GATHER_WAVES (GATHER_BLOCKS * 8)      // 4096

typedef __attribute__((ext_vector_type(8))) short bf16x8;
typedef __attribute__((ext_vector_type(4))) float f32x4;

__device__ __forceinline__ unsigned pack_bf16x2(float a, float b) {
    unsigned ua = __float_as_uint(a);
    ua = (ua + 0x7FFFu + ((ua >> 16) & 1u)) >> 16;   // RNE
    unsigned ub = __float_as_uint(b);
    ub = (ub + 0x7FFFu + ((ub >> 16) & 1u)) >> 16;
    return ua | (ub << 16);
}

__device__ __forceinline__ unsigned short bf16_1(float a) {
    unsigned u = __float_as_uint(a);
    return (unsigned short)((u + 0x7FFFu + ((u >> 16) & 1u)) >> 16);
}

__device__ __forceinline__ float blo(unsigned u) { return __uint_as_float(u << 16); }
__device__ __forceinline__ float bhi(unsigned u) { return __uint_as_float(u & 0xFFFF0000u); }

__device__ __forceinline__ unsigned pack_f16x2(float a, float b) {
    _Float16 ha = (_Float16)a, hb = (_Float16)b;
    return (unsigned)__builtin_bit_cast(unsigned short, ha) |
           ((unsigned)__builtin_bit_cast(unsigned short, hb) << 16);
}
__device__ __forceinline__ float f16lo(unsigned u) {
    return (float)__builtin_bit_cast(_Float16, (unsigned short)(u & 0xFFFFu));
}
__device__ __forceinline__ float f16hi(unsigned u) {
    return (float)__builtin_bit_cast(_Float16, (unsigned short)(u >> 16));
}

// ---- dispatch 1: per-block counting sort of 2048 edges into OWN bEdges region,
//      grouped by bucket; exclusive per-bucket offsets -> bOffsT[b][w].
//      Register shfl-scan. No device atomics. Extra block (A_BLOCKS) builds
//      the MFMA-B-layout bf16 W and zeroes the BN accumulators. ----
__global__ void __launch_bounds__(256) k_scat(const int* __restrict__ row,
                                              const int* __restrict__ col,
                                              unsigned* __restrict__ bEdges,
                                              int* __restrict__ bOffsT,
                                              const float* __restrict__ W,
                                              unsigned* __restrict__ WTn,
                                              float* __restrict__ sums8) {
    int tid = threadIdx.x, w = blockIdx.x;
    if (w == A_BLOCKS) {
        // WTn dword i = ((nt*4+kt)*64 + q*16+m)*4 + j  holds
        //   pack( W[kt*32+q*8+2j][nt*16+m], W[kt*32+q*8+2j+1][nt*16+m] )
#pragma unroll
        for (int it = 0; it < 32; ++it) {
            int i = tid + (it << 8);
            int j = i & 3, l = (i >> 2) & 63, kt = (i >> 8) & 3, nt = i >> 10;
            int m = l & 15, q = l >> 4;
            int kr = kt * 32 + q * 8 + 2 * j;
            int n = nt * 16 + m;
            WTn[i] = pack_bf16x2(W[kr * C + n], W[(kr + 1) * C + n]);
        }
        for (int i = tid; i < 2048; i += 256) sums8[i] = 0.f;
        return;
    }
    __shared__ int hist[NBUCK];
    __shared__ int wsum[8];
    int lane = tid & 63, wid = tid >> 6;
    for (int i = tid; i < NBUCK; i += 256) hist[i] = 0;
    __syncthreads();
    int e0 = w * EPB;
    int nE = N_EDGES - e0; if (nE > EPB) nE = EPB;
    int myc[8], myr[8];
#pragma unroll
    for (int k = 0; k < 8; ++k) {
        int idx = tid + (k << 8);
        bool ok = idx < nE;
        myc[k] = ok ? col[e0 + idx] : -1;
        myr[k] = ok ? row[e0 + idx] : 0;
        if (ok) atomicAdd(&hist[myc[k] >> BSHIFT], 1);
    }
    __syncthreads();
    // register scan over 391 buckets: positions tid and tid+256
    int v0 = hist[tid];
    int v1 = (tid + 256 < NBUCK) ? hist[tid + 256] : 0;
    int s0 = v0, s1 = v1;
#pragma unroll
    for (int d = 1; d < 64; d <<= 1) {
        int u0 = __shfl_up(s0, d, 64);
        int u1 = __shfl_up(s1, d, 64);
        if (lane >= d) { s0 += u0; s1 += u1; }
    }
    if (lane == 63) { wsum[wid] = s0; wsum[4 + wid] = s1; }
    __syncthreads();
    int tot0 = wsum[0] + wsum[1] + wsum[2] + wsum[3];
    int p0 = 0, p1 = tot0;
    for (int i = 0; i < wid; ++i) { p0 += wsum[i]; p1 += wsum[4 + i]; }
    int exc0 = p0 + s0 - v0;
    int exc1 = p1 + s1 - v1;
    bOffsT[tid * A_BLOCKS + w] = exc0;
    if (tid + 256 < NBUCK) bOffsT[(tid + 256) * A_BLOCKS + w] = exc1;
    if (tid == 0) bOffsT[NBUCK * A_BLOCKS + w] = nE;
    hist[tid] = exc0;                                   // cursors
    if (tid + 256 < NBUCK) hist[tid + 256] = exc1;
    __syncthreads();
#pragma unroll
    for (int k = 0; k < 8; ++k) {
        if (myc[k] >= 0) {
            int b = myc[k] >> BSHIFT;
            int r = atomicAdd(&hist[b], 1);  // LDS only
            bEdges[(size_t)w * EPB + r] = (unsigned)myr[k] | ((unsigned)myc[k] << 16);
        }
    }
}

// ---- dispatch 2: bsort (blocks 0..390) | gemm (blocks 391..1172).
//      Both depend only on k_scat; gemm writes UNSCALED bf16(x@W) (dinv
//      deferred to gather), so it needs no sort output. LDS unioned. ----
__global__ void __launch_bounds__(256) k_mid(const unsigned* __restrict__ bEdges,
                                             const int* __restrict__ bOffsT,
                                             int* __restrict__ offs,
                                             float* __restrict__ dinvArr,
                                             unsigned short* __restrict__ srcs,
                                             const float* __restrict__ x,
                                             const unsigned* __restrict__ WTn,
                                             unsigned short* __restrict__ g16) {
    __shared__ __align__(16) unsigned sm[4352];   // union: bsort 13.9KB | gemm 17.4KB
    __shared__ int wsum[12];
    __shared__ int wtot;
    int tid = threadIdx.x;
    int lane = tid & 63, wid = tid >> 6;
    if (blockIdx.x < NBUCK) {
        // ---- bsort bucket b ----
        const int b = blockIdx.x;
        int* sS = (int*)sm;                        // [391]
        int* sO = (int*)sm + 392;                  // [392]
        unsigned* ebuf = sm + 792;                 // [EBUF]
        int* h = (int*)(sm + 792 + EBUF);          // [128]
        int i1 = tid + 256;
        int st0 = bOffsT[b * A_BLOCKS + tid];
        int v0 = bOffsT[(b + 1) * A_BLOCKS + tid] - st0;
        int st1 = 0, v1 = 0;
        if (i1 < A_BLOCKS) {
            st1 = bOffsT[b * A_BLOCKS + i1];
            v1 = bOffsT[(b + 1) * A_BLOCKS + i1] - st1;
        }
        sS[tid] = st0;
        if (i1 < A_BLOCKS) sS[i1] = st1;
        if (tid < 128) h[tid] = 0;
        // e0 = sum of starts; scan of counts -> sO
        int ep = st0 + st1;
        int s0 = v0, s1 = v1;
#pragma unroll
        for (int d = 1; d < 64; d <<= 1) {
            int u0 = __shfl_up(s0, d, 64);
            int u1 = __shfl_up(s1, d, 64);
            if (lane >= d) { s0 += u0; s1 += u1; }
            ep += __shfl_xor(ep, d, 64);
        }
        if (lane == 63) { wsum[wid] = s0; wsum[4 + wid] = s1; }
        if (lane == 0) wsum[8 + wid] = ep;
        __syncthreads();
        int tot0 = wsum[0] + wsum[1] + wsum[2] + wsum[3];
        int tot1 = wsum[4] + wsum[5] + wsum[6] + wsum[7];
        int e0 = wsum[8] + wsum[9] + wsum[10] + wsum[11];
        int p0 = 0, p1 = tot0;
        for (int i = 0; i < wid; ++i) { p0 += wsum[i]; p1 += wsum[4 + i]; }
        sO[tid] = p0 + s0 - v0;
        if (i1 < A_BLOCKS) sO[i1] = p1 + s1 - v1;
        if (tid == 0) sO[A_BLOCKS] = tot0 + tot1;
        __syncthreads();
        int c = sO[A_BLOCKS];
        if (c > EBUF) c = EBUF;  // statistically impossible; memory-safety only
        // stage: each thread copies its segments sequentially (offsets known)
        for (int seg = tid; seg < A_BLOCKS; seg += 256) {
            int o = sO[seg];
            int n = sO[seg + 1] - o;
            const unsigned* srcp = bEdges + (size_t)seg * EPB + sS[seg];
            for (int k = 0; k < n; ++k) {
                int dp = o + k;
                if (dp < EBUF) ebuf[dp] = srcp[k];
            }
        }
        __syncthreads();
        int n0 = b << BSHIFT;
        int nn = N_NODES - n0; if (nn > 128) nn = 128;
        for (int e = tid; e < c; e += 256)
            atomicAdd(&h[(int)(ebuf[e] >> 16) - n0], 1);
        __syncthreads();
        int v = 0, sc = 0;
        if (tid < 128) {
            int ln = tid & 63;
            v = h[tid];
            sc = v;
#pragma unroll
            for (int d = 1; d < 64; d <<= 1) {
                int u = __shfl_up(sc, d, 64);
                if (ln >= d) sc += u;
            }
            if (tid == 63) wtot = sc;
        }
        __syncthreads();
        if (tid < 128) {
            int ex = sc - v + ((tid >= 64) ? wtot : 0);
            if (tid < nn) {
                offs[n0 + tid] = e0 + ex;
                dinvArr[n0 + tid] = rsqrtf((float)v + 1.f);
            }
            h[tid] = ex;  // reuse as cursor
        }
        __syncthreads();
        for (int e = tid; e < c; e += 256) {
            unsigned pe = ebuf[e];
            int r = atomicAdd(&h[(int)(pe >> 16) - n0], 1);
            srcs[e0 + r] = (unsigned short)(pe & 0xFFFFu);
        }
        if (b == NBUCK - 1 && tid == 0) offs[N_NODES] = N_EDGES;
    } else {
        // ---- gemm unit: 64 rows, unscaled g = bf16(x@W) ----
        unsigned* xs = sm;  // [64*68]
        int r0 = (blockIdx.x - NBUCK) * 64;
        const float4* x4 = (const float4*)x;
#pragma unroll
        for (int it = 0; it < 8; ++it) {
            int i = tid + (it << 8);
            int r = i >> 5, c4 = i & 31;
            float4 v = {0.f, 0.f, 0.f, 0.f};
            if (r0 + r < N_NODES) v = x4[(size_t)(r0 + r) * 32 + c4];
            xs[r * 68 + c4 * 2]     = pack_bf16x2(v.x, v.y);
            xs[r * 68 + c4 * 2 + 1] = pack_bf16x2(v.z, v.w);
        }
        __syncthreads();
        int r0w = r0 + wid * 16;
        if (r0w >= N_NODES) return;
        int m = lane & 15, q = lane >> 4;
        bf16x8 afrag[4];
#pragma unroll
        for (int kt = 0; kt < 4; ++kt)
            afrag[kt] = *(const bf16x8*)&xs[(wid * 16 + m) * 68 + kt * 16 + q * 4];
        const uint4* B4 = (const uint4*)WTn;
        f32x4 acc[8];
#pragma unroll
        for (int nt = 0; nt < 8; ++nt)
            acc[nt][0] = acc[nt][1] = acc[nt][2] = acc[nt][3] = 0.f;
#pragma unroll
        for (int nt = 0; nt < 8; ++nt) {
#pragma unroll
            for (int kt = 0; kt < 4; ++kt) {
                uint4 braw = B4[(nt * 4 + kt) * 64 + lane];   // coalesced 1 KB/instr
                bf16x8 bfrag = __builtin_bit_cast(bf16x8, braw);
                acc[nt] = __builtin_amdgcn_mfma_f32_16x16x32_bf16(afrag[kt], bfrag, acc[nt], 0, 0, 0);
            }
        }
        int rb = r0w + q * 4;
#pragma unroll
        for (int nt = 0; nt < 8; ++nt) {
            int cbase = nt * 16 + m;
#pragma unroll
            for (int reg = 0; reg < 4; ++reg)
                g16[(size_t)(rb + reg) * C + cbase] = bf16_1(acc[nt][reg]);
        }
    }
}

// ---- dispatch 3: gather + fused BN stats. One wave per node per iter;
//      16 channel-lanes x 4 source-slots; per-source dinv FMA (deferred
//      norm); per-block LDS partials -> 8-sliced sums8. ----
#define ACC8S(v, d) { a[0]+=blo(v.x)*d; a[1]+=bhi(v.x)*d; a[2]+=blo(v.y)*d; a[3]+=bhi(v.y)*d; \
                      a[4]+=blo(v.z)*d; a[5]+=bhi(v.z)*d; a[6]+=blo(v.w)*d; a[7]+=bhi(v.w)*d; }
__global__ void __launch_bounds__(512) k_gather(const int* __restrict__ offs,
                                                const unsigned short* __restrict__ srcs,
                                                const uint4* __restrict__ g4,
                                                const float* __restrict__ dinvArr,
                                                unsigned* __restrict__ aggh,
                                                float* __restrict__ sums8) {
    __shared__ float lsA[8][32][4], lsQ[8][32][4];
    int tid = threadIdx.x;
    int lane = tid & 63, wid = tid >> 6;
    int l = lane & 15, q = lane >> 4;
    float sA[4] = {0.f, 0.f, 0.f, 0.f}, sQ[4] = {0.f, 0.f, 0.f, 0.f};
    int gw = blockIdx.x * 8 + wid;
    for (int node = gw; node < N_NODES; node += GATHER_WAVES) {
        int beg = offs[node], end = offs[node + 1];
        float dt = dinvArr[node];
        float a[8];
        if (q == 0) {
            uint4 u = g4[(size_t)node * 16 + l];  // self-loop: *dt here, *dt again at end
            a[0]=blo(u.x)*dt; a[1]=bhi(u.x)*dt; a[2]=blo(u.y)*dt; a[3]=bhi(u.y)*dt;
            a[4]=blo(u.z)*dt; a[5]=bhi(u.z)*dt; a[6]=blo(u.w)*dt; a[7]=bhi(u.w)*dt;
        } else {
#pragma unroll
            for (int i = 0; i < 8; ++i) a[i] = 0.f;
        }
        for (int base = beg; base < end; base += 64) {
            int nb = end - base; if (nb > 64) nb = 64;
            int sv = (base + lane < end) ? (int)srcs[base + lane] : 0;
            int j0 = 0;
            for (; j0 + 16 <= nb; j0 += 16) {  // full groups: 4 loads in flight/lane
                int i0 = j0 + q;
                int s0 = __shfl(sv, i0, 64);
                int s1 = __shfl(sv, i0 + 4, 64);
                int s2 = __shfl(sv, i0 + 8, 64);
                int s3 = __shfl(sv, i0 + 12, 64);
                float d0 = dinvArr[s0], d1 = dinvArr[s1], d2 = dinvArr[s2], d3 = dinvArr[s3];
                uint4 v0 = g4[(size_t)s0 * 16 + l];
                uint4 v1 = g4[(size_t)s1 * 16 + l];
                uint4 v2 = g4[(size_t)s2 * 16 + l];
                uint4 v3 = g4[(size_t)s3 * 16 + l];
                ACC8S(v0, d0) ACC8S(v1, d1) ACC8S(v2, d2) ACC8S(v3, d3)
            }
            if (j0 < nb) {  // tail group
#pragma unroll
                for (int k = 0; k < 4; ++k) {
                    int idx = j0 + q + 4 * k;
                    int s = __shfl(sv, idx, 64);
                    if (idx < nb) {
                        float dd = dinvArr[s];
                        uint4 v = g4[(size_t)s * 16 + l];
                        ACC8S(v, dd)
                    }
                }
            }
        }
#pragma unroll
        for (int i = 0; i < 8; ++i) {
            a[i] += __shfl_xor(a[i], 16, 64);
            a[i] += __shfl_xor(a[i], 32, 64);
        }
        if (q < 2) {
            float f0 = a[q * 4 + 0] * dt, f1 = a[q * 4 + 1] * dt;
            float f2 = a[q * 4 + 2] * dt, f3 = a[q * 4 + 3] * dt;
            sA[0] += f0; sQ[0] += f0 * f0;
            sA[1] += f1; sQ[1] += f1 * f1;
            sA[2] += f2; sQ[2] += f2 * f2;
            sA[3] += f3; sQ[3] += f3 * f3;
            uint2 pv; pv.x = pack_f16x2(f0, f1); pv.y = pack_f16x2(f2, f3);
            *(uint2*)(aggh + (size_t)node * 64 + l * 4 + q * 2) = pv;
        }
    }
    if (q < 2) {
#pragma unroll
        for (int i = 0; i < 4; ++i) {
            lsA[wid][l * 2 + q][i] = sA[i];
            lsQ[wid][l * 2 + q][i] = sQ[i];
        }
    }
    __syncthreads();
    if (tid < 128) {
        int ll = tid >> 3, qq = (tid >> 2) & 1, ii = tid & 3;
        float s = 0.f, sq = 0.f;
#pragma unroll
        for (int wd = 0; wd < 8; ++wd) {
            s  += lsA[wd][ll * 2 + qq][ii];
            sq += lsQ[wd][ll * 2 + qq][ii];
        }
        int slice = (blockIdx.x & 7) * 256;
        atomicAdd(&sums8[slice + tid], s);
        atomicAdd(&sums8[slice + 128 + tid], sq);
    }
}

// ---- dispatch 4: y = relu(aggh*scale + shift) -> f32 out; bias cancels in BN ----
__global__ void __launch_bounds__(256) k_final(const unsigned* __restrict__ aggh,
                                               float* __restrict__ out,
                                               const float* __restrict__ sums8,
                                               const float* __restrict__ gamma,
                                               const float* __restrict__ beta) {
    __shared__ float sc_s[C], sh_s[C];
    int tid = threadIdx.x;
    if (tid < C) {
        float s = 0.f, sq = 0.f;
#pragma unroll
        for (int k = 0; k < 8; ++k) {
            s  += sums8[k * 256 + tid];
            sq += sums8[k * 256 + 128 + tid];
        }
        float mean = s * (1.0f / N_NODES);
        float var = sq * (1.0f / N_NODES) - mean * mean;
        float sc = gamma[tid] * rsqrtf(var + BN_EPS);
        sc_s[tid] = sc;
        sh_s[tid] = beta[tid] - mean * sc;
    }
    __syncthreads();
    int i = blockIdx.x * 256 + tid;          // uint4 index over aggh, N*16 total
    uint4 v = ((const uint4*)aggh)[i];
    int c = (i & 15) * 8;
    float4 o0, o1;
    o0.x = fmaxf(f16lo(v.x) * sc_s[c+0] + sh_s[c+0], 0.f);
    o0.y = fmaxf(f16hi(v.x) * sc_s[c+1] + sh_s[c+1], 0.f);
    o0.z = fmaxf(f16lo(v.y) * sc_s[c+2] + sh_s[c+2], 0.f);
    o0.w = fmaxf(f16hi(v.y) * sc_s[c+3] + sh_s[c+3], 0.f);
    o1.x = fmaxf(f16lo(v.z) * sc_s[c+4] + sh_s[c+4], 0.f);
    o1.y = fmaxf(f16hi(v.z) * sc_s[c+5] + sh_s[c+5], 0.f);
    o1.z = fmaxf(f16lo(v.w) * sc_s[c+6] + sh_s[c+6], 0.f);
    o1.w = fmaxf(f16hi(v.w) * sc_s[c+7] + sh_s[c+7], 0.f);
    float4* o = (float4*)(out + (size_t)i * 8);
    o[0] = o0; o[1] = o1;
}

extern "C" void kernel_launch(void* const* d_in, const int* in_sizes, int n_in,
                              void* d_out, int out_size, void* d_ws, size_t ws_size,
                              hipStream_t stream) {
    const float* x     = (const float*)d_in[0];
    const float* W     = (const float*)d_in[1];
    // d_in[2] = bias: cancels in BatchNorm, unused
    const float* gamma = (const float*)d_in[3];
    const float* beta  = (const float*)d_in[4];
    const int*   eidx  = (const int*)d_in[5];
    const int* row = eidx;
    const int* col = eidx + N_EDGES;

    float* out = (float*)d_out;  // [N, C] f32

    // workspace layout (all 16B-aligned)
    unsigned* g      = (unsigned*)d_ws;                          // [N*64] bf16x2 rows (12.8 MB)
    unsigned* aggh   = g + (size_t)N_NODES * 64;                 // [N*64] f16x2 rows (12.8 MB)
    unsigned* bEdges = aggh + (size_t)N_NODES * 64;              // [A_BLOCKS*EPB] (3.2 MB)
    unsigned* WTn    = bEdges + (size_t)A_BLOCKS * EPB;          // [8192] bf16x2 (W, MFMA-B layout)
    unsigned short* srcs = (unsigned short*)(WTn + 8192);        // [E] u16 (1.6 MB)
    int*   offs    = (int*)(srcs + N_EDGES);                     // [N+1] (+3 pad)
    float* dinvArr = (float*)(offs + N_NODES + 4);               // [N]
    float* sums8   = dinvArr + N_NODES;                          // [8*256] sliced BN accum
    int*   bOffsT  = (int*)(sums8 + 2048);                       // [(NBUCK+1)*A_BLOCKS] (613 KB)

    k_scat<<<A_BLOCKS + 1, 256, 0, stream>>>(row, col, bEdges, bOffsT, W, WTn, sums8);
    k_mid<<<NBUCK + GEMM_BLOCKS, 256, 0, stream>>>(bEdges, bOffsT, offs, dinvArr, srcs,
                                                   x, WTn, (unsigned short*)g);
    k_gather<<<GATHER_BLOCKS, 512, 0, stream>>>(offs, srcs, (const uint4*)g, dinvArr, aggh, sums8);
    k_final<<<N_NODES * 16 / 256, 256, 0, stream>>>(aggh, out, sums8, gamma, beta);
}